// Round 1
// baseline (470.731 us; speedup 1.0000x reference)
//
#include <hip/hip_runtime.h>
#include <hip/hip_bf16.h>
#include <math.h>

// Problem constants (fixed by setup_inputs)
constexpr int B  = 4;
constexpr int Q  = 1024;
constexpr int D  = 256;
constexpr int NH = 8;
constexpr int NP = 4;
constexpr int H  = 128;
constexpr int W  = 128;
constexpr int HW = H * W;

// ---------------------------------------------------------------------------
// Kernel A: offsets + attention logits + softmax -> locs, attn weights
// One block per (b,q) row. 128 threads.
// ---------------------------------------------------------------------------
__global__ __launch_bounds__(128)
void k_offsets(const float* __restrict__ query,
               const float* __restrict__ refpts,
               const float* __restrict__ W_off,  const float* __restrict__ b_off,
               const float* __restrict__ W_attn, const float* __restrict__ b_attn,
               float* __restrict__ locs, float* __restrict__ attnw) {
    const int bq = blockIdx.x;         // 0..B*Q-1
    const int t  = threadIdx.x;        // 0..127
    __shared__ float qrow[D];
    __shared__ float logits[NH * NP];

    const float* qp = query + (size_t)bq * D;
    for (int i = t; i < D; i += 128) qrow[i] = qp[i];
    __syncthreads();

    if (t < 64) {
        // offset output j = t, layout [nh, np, 2] flattened
        float acc = b_off[t];
        #pragma unroll 4
        for (int k = 0; k < D; ++k) acc += qrow[k] * W_off[k * 64 + t];
        const int c = t & 1;
        const float ref = refpts[(size_t)bq * 2 + c];
        float loc = ref + acc * 0.1f;
        loc = fminf(fmaxf(loc, 0.0f), 1.0f) * 2.0f - 1.0f;
        locs[(size_t)bq * 64 + t] = loc;
    } else if (t < 96) {
        const int j = t - 64;          // 0..31 = h*NP+p
        float acc = b_attn[j];
        #pragma unroll 4
        for (int k = 0; k < D; ++k) acc += qrow[k] * W_attn[k * 32 + j];
        logits[j] = acc;
    }
    __syncthreads();

    if (t < NH) {
        float m = -1e30f;
        #pragma unroll
        for (int p = 0; p < NP; ++p) m = fmaxf(m, logits[t * NP + p]);
        float e[NP];
        float s = 0.0f;
        #pragma unroll
        for (int p = 0; p < NP; ++p) { e[p] = __expf(logits[t * NP + p] - m); s += e[p]; }
        const float inv = 1.0f / s;
        #pragma unroll
        for (int p = 0; p < NP; ++p)
            attnw[(size_t)bq * (NH * NP) + t * NP + p] = e[p] * inv;
    }
}

// ---------------------------------------------------------------------------
// Kernel B/D: fp32 SGEMM  C[M,N] = A[M,K] @ Bm[K,N] + bias[N]
// 64x64 tile, 256 threads, 4x4 microtile, BK=16.
// Requires M%64==0, N%64==0, K%16==0 (holds for both uses).
// ---------------------------------------------------------------------------
#define BM 64
#define BN 64
#define BK 16

__global__ __launch_bounds__(256)
void k_sgemm(const float* __restrict__ A, const float* __restrict__ Bm,
             const float* __restrict__ bias, float* __restrict__ C,
             int M, int N, int K) {
    __shared__ __align__(16) float As[BK][BM + 4];
    __shared__ __align__(16) float Bs[BK][BN + 4];

    const int t  = threadIdx.x;
    const int tx = t & 15;           // 0..15 -> 4 cols each
    const int ty = t >> 4;           // 0..15 -> 4 rows each
    const int m0 = blockIdx.x * BM;
    const int n0 = blockIdx.y * BN;

    // loader indices
    const int arow = t >> 2;         // 0..63
    const int akg  = (t & 3) * 4;    // 0,4,8,12
    const int brow = t >> 4;         // 0..15
    const int bcol = (t & 15) * 4;   // 0..60

    float acc[4][4] = {};

    for (int k0 = 0; k0 < K; k0 += BK) {
        const float4 av = *(const float4*)&A[(size_t)(m0 + arow) * K + k0 + akg];
        const float4 bv = *(const float4*)&Bm[(size_t)(k0 + brow) * N + n0 + bcol];
        __syncthreads();
        As[akg + 0][arow] = av.x;
        As[akg + 1][arow] = av.y;
        As[akg + 2][arow] = av.z;
        As[akg + 3][arow] = av.w;
        *(float4*)&Bs[brow][bcol] = bv;
        __syncthreads();

        #pragma unroll
        for (int kk = 0; kk < BK; ++kk) {
            const float4 a = *(const float4*)&As[kk][ty * 4];
            const float4 b = *(const float4*)&Bs[kk][tx * 4];
            acc[0][0] += a.x * b.x; acc[0][1] += a.x * b.y; acc[0][2] += a.x * b.z; acc[0][3] += a.x * b.w;
            acc[1][0] += a.y * b.x; acc[1][1] += a.y * b.y; acc[1][2] += a.y * b.z; acc[1][3] += a.y * b.w;
            acc[2][0] += a.z * b.x; acc[2][1] += a.z * b.y; acc[2][2] += a.z * b.z; acc[2][3] += a.z * b.w;
            acc[3][0] += a.w * b.x; acc[3][1] += a.w * b.y; acc[3][2] += a.w * b.z; acc[3][3] += a.w * b.w;
        }
    }

    const float4 bb = *(const float4*)&bias[n0 + tx * 4];
    #pragma unroll
    for (int i = 0; i < 4; ++i) {
        const int m = m0 + ty * 4 + i;
        float4 r;
        r.x = acc[i][0] + bb.x;
        r.y = acc[i][1] + bb.y;
        r.z = acc[i][2] + bb.z;
        r.w = acc[i][3] + bb.w;
        *(float4*)&C[(size_t)m * N + n0 + tx * 4] = r;
    }
}

// ---------------------------------------------------------------------------
// Kernel C: bilinear sample 4 points + weighted sum over points.
// One block per (b,q,h); thread d handles channel d.
// ---------------------------------------------------------------------------
__global__ __launch_bounds__(256)
void k_sample(const float* __restrict__ img,    // [B,H,W,D]
              const float* __restrict__ locs,   // [B,Q,NH,NP,2]
              const float* __restrict__ attnw,  // [B,Q,NH,NP]
              float* __restrict__ weighted) {   // [B,Q,NH,D]
    const int idx = blockIdx.x;                 // b*Q*NH + q*NH + h
    const int b   = idx / (Q * NH);
    const int d   = threadIdx.x;                // 0..255

    const float* lp = locs  + (size_t)idx * (NP * 2);
    const float* ap = attnw + (size_t)idx * NP;
    const float* ib = img   + (size_t)b * HW * D;

    float acc = 0.0f;
    #pragma unroll
    for (int p = 0; p < NP; ++p) {
        const float gx = lp[p * 2 + 0];
        const float gy = lp[p * 2 + 1];
        const float x  = ((gx + 1.0f) * (float)W - 1.0f) * 0.5f;
        const float y  = ((gy + 1.0f) * (float)H - 1.0f) * 0.5f;
        const float x0f = floorf(x);
        const float y0f = floorf(y);
        const float wx1 = x - x0f;
        const float wy1 = y - y0f;
        const float wx0 = 1.0f - wx1;
        const float wy0 = 1.0f - wy1;
        const int x0 = (int)x0f;
        const int y0 = (int)y0f;
        const int x1 = x0 + 1;
        const int y1 = y0 + 1;
        const float a = ap[p];

        const bool vx0 = (x0 >= 0) & (x0 < W);
        const bool vx1 = (x1 >= 0) & (x1 < W);
        const bool vy0 = (y0 >= 0) & (y0 < H);
        const bool vy1 = (y1 >= 0) & (y1 < H);

        float v00 = 0.0f, v10 = 0.0f, v01 = 0.0f, v11 = 0.0f;
        if (vy0 & vx0) v00 = ib[((size_t)y0 * W + x0) * D + d];
        if (vy0 & vx1) v10 = ib[((size_t)y0 * W + x1) * D + d];
        if (vy1 & vx0) v01 = ib[((size_t)y1 * W + x0) * D + d];
        if (vy1 & vx1) v11 = ib[((size_t)y1 * W + x1) * D + d];

        acc += a * (v00 * wx0 * wy0 + v10 * wx1 * wy0 +
                    v01 * wx0 * wy1 + v11 * wx1 * wy1);
    }
    weighted[(size_t)idx * D + d] = acc;
}

// ---------------------------------------------------------------------------
extern "C" void kernel_launch(void* const* d_in, const int* in_sizes, int n_in,
                              void* d_out, int out_size, void* d_ws, size_t ws_size,
                              hipStream_t stream) {
    const float* query  = (const float*)d_in[0];
    const float* refpts = (const float*)d_in[1];
    const float* value  = (const float*)d_in[2];
    const float* W_off  = (const float*)d_in[3];
    const float* b_off  = (const float*)d_in[4];
    const float* W_attn = (const float*)d_in[5];
    const float* b_attn = (const float*)d_in[6];
    const float* W_v    = (const float*)d_in[7];
    const float* b_v    = (const float*)d_in[8];
    const float* W_out  = (const float*)d_in[9];
    const float* b_out  = (const float*)d_in[10];
    float* out = (float*)d_out;

    float* ws       = (float*)d_ws;
    float* img      = ws;                                      // B*HW*D      = 16,777,216
    float* locs     = img   + (size_t)B * HW * D;              // B*Q*NH*NP*2 =    262,144
    float* attnw    = locs  + (size_t)B * Q * NH * NP * 2;     // B*Q*NH*NP   =    131,072
    float* weighted = attnw + (size_t)B * Q * NH * NP;         // B*Q*NH*D    =  8,388,608

    // A: offsets + attention weights
    k_offsets<<<B * Q, 128, 0, stream>>>(query, refpts, W_off, b_off,
                                         W_attn, b_attn, locs, attnw);

    // B: img = value @ W_v + b_v   (M=65536, N=256, K=256)
    {
        dim3 grid((B * HW) / BM, D / BN);
        k_sgemm<<<grid, 256, 0, stream>>>(value, W_v, b_v, img, B * HW, D, D);
    }

    // C: bilinear sampling + weighted reduce over points
    k_sample<<<B * Q * NH, 256, 0, stream>>>(img, locs, attnw, weighted);

    // D: out = weighted[B*Q, NH*D] @ W_out + b_out  (M=4096, N=256, K=2048)
    {
        dim3 grid((B * Q) / BM, D / BN);
        k_sgemm<<<grid, 256, 0, stream>>>(weighted, W_out, b_out, out,
                                          B * Q, D, NH * D);
    }
}

// Round 2
// 310.400 us; speedup vs baseline: 1.5165x; 1.5165x over previous
//
#include <hip/hip_runtime.h>
#include <hip/hip_bf16.h>
#include <math.h>

// Problem constants (fixed by setup_inputs)
constexpr int B  = 4;
constexpr int Q  = 1024;
constexpr int D  = 256;
constexpr int NH = 8;
constexpr int NP = 4;
constexpr int H  = 128;
constexpr int W  = 128;
constexpr int HW = H * W;

typedef short   bf16x8  __attribute__((ext_vector_type(8)));
typedef float   f32x4   __attribute__((ext_vector_type(4)));
typedef short   short4v __attribute__((ext_vector_type(4)));

__device__ inline unsigned short f2bf(float f) {
    union { float f; unsigned u; } v; v.f = f;
    unsigned r = v.u + 0x7fff + ((v.u >> 16) & 1);   // RNE
    return (unsigned short)(r >> 16);
}
__device__ inline float bf2f(unsigned short s) {
    union { unsigned u; float f; } v; v.u = ((unsigned)s) << 16;
    return v.f;
}

// async global->LDS, 16B per lane. LDS dest = wave-uniform base + lane*16.
__device__ inline void async16(const void* g, void* l) {
    __builtin_amdgcn_global_load_lds(
        (const __attribute__((address_space(1))) unsigned*)g,
        (__attribute__((address_space(3))) unsigned*)l, 16, 0, 0);
}

// ---------------------------------------------------------------------------
// Kernel A: offsets + attention logits + softmax -> locs, attn weights
// ---------------------------------------------------------------------------
__global__ __launch_bounds__(128)
void k_offsets(const float* __restrict__ query,
               const float* __restrict__ refpts,
               const float* __restrict__ W_off,  const float* __restrict__ b_off,
               const float* __restrict__ W_attn, const float* __restrict__ b_attn,
               float* __restrict__ locs, float* __restrict__ attnw) {
    const int bq = blockIdx.x;
    const int t  = threadIdx.x;
    __shared__ float qrow[D];
    __shared__ float logits[NH * NP];

    const float* qp = query + (size_t)bq * D;
    for (int i = t; i < D; i += 128) qrow[i] = qp[i];
    __syncthreads();

    if (t < 64) {
        float acc = b_off[t];
        #pragma unroll 4
        for (int k = 0; k < D; ++k) acc += qrow[k] * W_off[k * 64 + t];
        const int c = t & 1;
        const float ref = refpts[(size_t)bq * 2 + c];
        float loc = ref + acc * 0.1f;
        loc = fminf(fmaxf(loc, 0.0f), 1.0f) * 2.0f - 1.0f;
        locs[(size_t)bq * 64 + t] = loc;
    } else if (t < 96) {
        const int j = t - 64;
        float acc = b_attn[j];
        #pragma unroll 4
        for (int k = 0; k < D; ++k) acc += qrow[k] * W_attn[k * 32 + j];
        logits[j] = acc;
    }
    __syncthreads();

    if (t < NH) {
        float m = -1e30f;
        #pragma unroll
        for (int p = 0; p < NP; ++p) m = fmaxf(m, logits[t * NP + p]);
        float e[NP]; float s = 0.0f;
        #pragma unroll
        for (int p = 0; p < NP; ++p) { e[p] = __expf(logits[t * NP + p] - m); s += e[p]; }
        const float inv = 1.0f / s;
        #pragma unroll
        for (int p = 0; p < NP; ++p)
            attnw[(size_t)bq * (NH * NP) + t * NP + p] = e[p] * inv;
    }
}

// ---------------------------------------------------------------------------
// fp32 -> bf16 elementwise convert (vectorized, n % 1024 == 0)
// ---------------------------------------------------------------------------
__global__ __launch_bounds__(256)
void k_conv(const float* __restrict__ src, unsigned short* __restrict__ dst, int n) {
    const int i = (blockIdx.x * 256 + threadIdx.x) * 4;
    if (i >= n) return;
    const float4 v = *(const float4*)&src[i];
    short4v o;
    o.x = (short)f2bf(v.x); o.y = (short)f2bf(v.y);
    o.z = (short)f2bf(v.z); o.w = (short)f2bf(v.w);
    *(short4v*)&dst[i] = o;
}

// ---------------------------------------------------------------------------
// fp32 [K,N] -> bf16 transposed [N,K] (tiny weight matrices)
// ---------------------------------------------------------------------------
__global__ __launch_bounds__(256)
void k_convt(const float* __restrict__ src, unsigned short* __restrict__ dst,
             int K, int N) {
    const int i = blockIdx.x * 256 + threadIdx.x;   // over N*K outputs
    if (i >= N * K) return;
    const int n = i / K, k = i % K;
    dst[i] = f2bf(src[(size_t)k * N + n]);
}

// ---------------------------------------------------------------------------
// bf16 MFMA GEMM: C[M,N] = A[M,K] @ Bt[N,K]^T + bias[N]
// 128x128 tile, 256 thr (4 waves, 2x2 of 64x64), BK=32, 16x16x32 MFMA,
// global_load_lds width-16 staging (m97 structure).
// Requires M%128==0, N%128==0, K%32==0.
// ---------------------------------------------------------------------------
template <bool BF16OUT>
__global__ __launch_bounds__(256)
void k_gemm_bf16(const unsigned short* __restrict__ A,
                 const unsigned short* __restrict__ Bt,
                 const float* __restrict__ bias, void* __restrict__ Cout,
                 int M, int N, int K) {
    __shared__ __align__(16) unsigned short As[128 * 32];
    __shared__ __align__(16) unsigned short Bs[128 * 32];

    const int tid  = threadIdx.x;
    const int lane = tid & 63;
    const int w    = tid >> 6;
    const int wm   = w >> 1, wn = w & 1;
    const int m0   = blockIdx.x * 128, n0 = blockIdx.y * 128;

    // staging: thread tid loads row tid/4, 16B chunk tid%4 (and +64 rows)
    const unsigned short* ag0 = A  + (size_t)(m0 + (tid >> 2)) * K + (tid & 3) * 8;
    const unsigned short* ag1 = ag0 + (size_t)64 * K;
    const unsigned short* bg0 = Bt + (size_t)(n0 + (tid >> 2)) * K + (tid & 3) * 8;
    const unsigned short* bg1 = bg0 + (size_t)64 * K;
    unsigned short* al0 = As + tid * 8;
    unsigned short* al1 = As + 2048 + tid * 8;
    unsigned short* bl0 = Bs + tid * 8;
    unsigned short* bl1 = Bs + 2048 + tid * 8;

    // fragment LDS offsets (shorts): row-major [128][32]
    int aoff[4], boff[4];
    #pragma unroll
    for (int t = 0; t < 4; ++t) {
        aoff[t] = (wm * 64 + t * 16 + (lane & 15)) * 32 + (lane >> 4) * 8;
        boff[t] = (wn * 64 + t * 16 + (lane & 15)) * 32 + (lane >> 4) * 8;
    }

    f32x4 acc[4][4];
    #pragma unroll
    for (int i = 0; i < 4; ++i)
        #pragma unroll
        for (int j = 0; j < 4; ++j) acc[i][j] = (f32x4){0.f, 0.f, 0.f, 0.f};

    for (int k0 = 0; k0 < K; k0 += 32) {
        async16(ag0, al0); async16(ag1, al1);
        async16(bg0, bl0); async16(bg1, bl1);
        ag0 += 32; ag1 += 32; bg0 += 32; bg1 += 32;
        __syncthreads();                       // drains vmcnt -> LDS visible

        bf16x8 af[4], bfr[4];
        #pragma unroll
        for (int t = 0; t < 4; ++t) {
            af[t]  = *(const bf16x8*)&As[aoff[t]];
            bfr[t] = *(const bf16x8*)&Bs[boff[t]];
        }
        #pragma unroll
        for (int i = 0; i < 4; ++i)
            #pragma unroll
            for (int j = 0; j < 4; ++j)
                acc[i][j] = __builtin_amdgcn_mfma_f32_16x16x32_bf16(
                    af[i], bfr[j], acc[i][j], 0, 0, 0);
        __syncthreads();                       // protect LDS before next stage
    }

    // epilogue: C/D layout col=lane&15, row=(lane>>4)*4+reg
    const int colb = n0 + wn * 64 + (lane & 15);
    const int rowb = m0 + wm * 64 + (lane >> 4) * 4;
    #pragma unroll
    for (int tn = 0; tn < 4; ++tn) {
        const int col = colb + tn * 16;
        const float bb = bias[col];
        #pragma unroll
        for (int tm = 0; tm < 4; ++tm) {
            #pragma unroll
            for (int r = 0; r < 4; ++r) {
                const int row = rowb + tm * 16 + r;
                const float val = acc[tm][tn][r] + bb;
                if (BF16OUT)
                    ((unsigned short*)Cout)[(size_t)row * N + col] = f2bf(val);
                else
                    ((float*)Cout)[(size_t)row * N + col] = val;
            }
        }
    }
}

// ---------------------------------------------------------------------------
// Kernel C: bilinear sample (bf16 img) + weighted sum over points -> bf16
// ---------------------------------------------------------------------------
__global__ __launch_bounds__(256)
void k_sample(const unsigned short* __restrict__ img,   // [B,H,W,D] bf16
              const float* __restrict__ locs,           // [B,Q,NH,NP,2]
              const float* __restrict__ attnw,          // [B,Q,NH,NP]
              unsigned short* __restrict__ weighted) {  // [B,Q,NH,D] bf16
    const int idx = blockIdx.x;                 // b*Q*NH + q*NH + h
    const int b   = idx / (Q * NH);
    const int d   = threadIdx.x;

    const float* lp = locs  + (size_t)idx * (NP * 2);
    const float* ap = attnw + (size_t)idx * NP;
    const unsigned short* ib = img + (size_t)b * HW * D;

    float acc = 0.0f;
    #pragma unroll
    for (int p = 0; p < NP; ++p) {
        const float gx = lp[p * 2 + 0];
        const float gy = lp[p * 2 + 1];
        const float x  = ((gx + 1.0f) * (float)W - 1.0f) * 0.5f;
        const float y  = ((gy + 1.0f) * (float)H - 1.0f) * 0.5f;
        const float x0f = floorf(x);
        const float y0f = floorf(y);
        const float wx1 = x - x0f;
        const float wy1 = y - y0f;
        const float wx0 = 1.0f - wx1;
        const float wy0 = 1.0f - wy1;
        const int x0 = (int)x0f, y0 = (int)y0f;
        const int x1 = x0 + 1,  y1 = y0 + 1;
        const float a = ap[p];

        const bool vx0 = (x0 >= 0) & (x0 < W);
        const bool vx1 = (x1 >= 0) & (x1 < W);
        const bool vy0 = (y0 >= 0) & (y0 < H);
        const bool vy1 = (y1 >= 0) & (y1 < H);

        float v00 = 0.f, v10 = 0.f, v01 = 0.f, v11 = 0.f;
        if (vy0 & vx0) v00 = bf2f(ib[((size_t)y0 * W + x0) * D + d]);
        if (vy0 & vx1) v10 = bf2f(ib[((size_t)y0 * W + x1) * D + d]);
        if (vy1 & vx0) v01 = bf2f(ib[((size_t)y1 * W + x0) * D + d]);
        if (vy1 & vx1) v11 = bf2f(ib[((size_t)y1 * W + x1) * D + d]);

        acc += a * (v00 * wx0 * wy0 + v10 * wx1 * wy0 +
                    v01 * wx0 * wy1 + v11 * wx1 * wy1);
    }
    weighted[(size_t)idx * D + d] = f2bf(acc);   // contiguous [B*Q, NH*D]
}

// ---------------------------------------------------------------------------
extern "C" void kernel_launch(void* const* d_in, const int* in_sizes, int n_in,
                              void* d_out, int out_size, void* d_ws, size_t ws_size,
                              hipStream_t stream) {
    const float* query  = (const float*)d_in[0];
    const float* refpts = (const float*)d_in[1];
    const float* value  = (const float*)d_in[2];
    const float* W_off  = (const float*)d_in[3];
    const float* b_off  = (const float*)d_in[4];
    const float* W_attn = (const float*)d_in[5];
    const float* b_attn = (const float*)d_in[6];
    const float* W_v    = (const float*)d_in[7];
    const float* b_v    = (const float*)d_in[8];
    const float* W_out  = (const float*)d_in[9];
    const float* b_out  = (const float*)d_in[10];
    float* out = (float*)d_out;

    // workspace layout (float slots; all 16B aligned)
    float* ws = (float*)d_ws;
    unsigned short* img_bf  = (unsigned short*)ws;                   // 64*256*256*... B*HW*D bf16 = 32MB
    unsigned short* val_bf  = (unsigned short*)(ws + 8388608);       // B*HW*D bf16 = 32MB
    float*          locs    = ws + 2 * 8388608;                      // 1MB
    float*          attnw   = locs + 262144;                         // 0.5MB
    unsigned short* Wv_t    = (unsigned short*)(attnw + 131072);     // 128KB
    unsigned short* Wout_t  = (unsigned short*)(attnw + 131072 + 32768); // 1MB
    unsigned short* wtd_bf  = val_bf;  // weighted aliases val_bf (dead after GEMM B)

    // A: offsets + attention weights
    k_offsets<<<B * Q, 128, 0, stream>>>(query, refpts, W_off, b_off,
                                         W_attn, b_attn, locs, attnw);

    // converts
    k_conv<<<(B * HW * D) / 1024, 256, 0, stream>>>(value, val_bf, B * HW * D);
    k_convt<<<(D * D) / 256, 256, 0, stream>>>(W_v, Wv_t, D, D);            // [256,256] -> [256,256]^T
    k_convt<<<(NH * D * D) / 256, 256, 0, stream>>>(W_out, Wout_t, NH * D, D); // [2048,256] -> [256,2048]

    // B: img = value @ W_v + b_v   (M=65536, N=256, K=256) -> bf16
    {
        dim3 grid((B * HW) / 128, D / 128);
        k_gemm_bf16<true><<<grid, 256, 0, stream>>>(val_bf, Wv_t, b_v, img_bf,
                                                    B * HW, D, D);
    }

    // C: bilinear sampling + weighted reduce -> bf16 [B*Q, NH*D]
    k_sample<<<B * Q * NH, 256, 0, stream>>>(img_bf, locs, attnw, wtd_bf);

    // D: out = weighted @ W_out + b_out  (M=4096, N=256, K=2048) -> fp32
    {
        dim3 grid((B * Q) / 128, D / 128);
        k_gemm_bf16<false><<<grid, 256, 0, stream>>>(wtd_bf, Wout_t, b_out, out,
                                                     B * Q, D, NH * D);
    }
}

// Round 3
// 240.249 us; speedup vs baseline: 1.9593x; 1.2920x over previous
//
#include <hip/hip_runtime.h>
#include <hip/hip_bf16.h>
#include <math.h>

// Problem constants (fixed by setup_inputs)
constexpr int B  = 4;
constexpr int Q  = 1024;
constexpr int D  = 256;
constexpr int NH = 8;
constexpr int NP = 4;
constexpr int H  = 128;
constexpr int W  = 128;
constexpr int HW = H * W;

typedef short   bf16x8  __attribute__((ext_vector_type(8)));
typedef float   f32x4   __attribute__((ext_vector_type(4)));
typedef short   short4v __attribute__((ext_vector_type(4)));
typedef unsigned short ushort4v __attribute__((ext_vector_type(4)));

__device__ inline unsigned short f2bf(float f) {
    union { float f; unsigned u; } v; v.f = f;
    unsigned r = v.u + 0x7fff + ((v.u >> 16) & 1);   // RNE
    return (unsigned short)(r >> 16);
}
__device__ inline float bf2f(unsigned short s) {
    union { unsigned u; float f; } v; v.u = ((unsigned)s) << 16;
    return v.f;
}

// async global->LDS, 16B per lane. LDS dest = wave-uniform base + lane*16.
__device__ inline void async16(const void* g, void* l) {
    __builtin_amdgcn_global_load_lds(
        (const __attribute__((address_space(1))) unsigned*)g,
        (__attribute__((address_space(3))) unsigned*)l, 16, 0, 0);
}

// ---------------------------------------------------------------------------
// Kernel A: offsets + attention logits + softmax -> locs, attn weights
// ---------------------------------------------------------------------------
__global__ __launch_bounds__(128)
void k_offsets(const float* __restrict__ query,
               const float* __restrict__ refpts,
               const float* __restrict__ W_off,  const float* __restrict__ b_off,
               const float* __restrict__ W_attn, const float* __restrict__ b_attn,
               float* __restrict__ locs, float* __restrict__ attnw) {
    const int bq = blockIdx.x;
    const int t  = threadIdx.x;
    __shared__ float qrow[D];
    __shared__ float logits[NH * NP];

    const float* qp = query + (size_t)bq * D;
    for (int i = t; i < D; i += 128) qrow[i] = qp[i];
    __syncthreads();

    if (t < 64) {
        float acc = b_off[t];
        #pragma unroll 4
        for (int k = 0; k < D; ++k) acc += qrow[k] * W_off[k * 64 + t];
        const int c = t & 1;
        const float ref = refpts[(size_t)bq * 2 + c];
        float loc = ref + acc * 0.1f;
        loc = fminf(fmaxf(loc, 0.0f), 1.0f) * 2.0f - 1.0f;
        locs[(size_t)bq * 64 + t] = loc;
    } else if (t < 96) {
        const int j = t - 64;
        float acc = b_attn[j];
        #pragma unroll 4
        for (int k = 0; k < D; ++k) acc += qrow[k] * W_attn[k * 32 + j];
        logits[j] = acc;
    }
    __syncthreads();

    if (t < NH) {
        float m = -1e30f;
        #pragma unroll
        for (int p = 0; p < NP; ++p) m = fmaxf(m, logits[t * NP + p]);
        float e[NP]; float s = 0.0f;
        #pragma unroll
        for (int p = 0; p < NP; ++p) { e[p] = __expf(logits[t * NP + p] - m); s += e[p]; }
        const float inv = 1.0f / s;
        #pragma unroll
        for (int p = 0; p < NP; ++p)
            attnw[(size_t)bq * (NH * NP) + t * NP + p] = e[p] * inv;
    }
}

// ---------------------------------------------------------------------------
// fp32 -> bf16 elementwise convert (vectorized, n % 1024 == 0)
// ---------------------------------------------------------------------------
__global__ __launch_bounds__(256)
void k_conv(const float* __restrict__ src, unsigned short* __restrict__ dst, int n) {
    const int i = (blockIdx.x * 256 + threadIdx.x) * 4;
    if (i >= n) return;
    const float4 v = *(const float4*)&src[i];
    short4v o;
    o.x = (short)f2bf(v.x); o.y = (short)f2bf(v.y);
    o.z = (short)f2bf(v.z); o.w = (short)f2bf(v.w);
    *(short4v*)&dst[i] = o;
}

// ---------------------------------------------------------------------------
// fp32 [K,N] -> bf16 transposed [N,K] (tiny weight matrices)
// ---------------------------------------------------------------------------
__global__ __launch_bounds__(256)
void k_convt(const float* __restrict__ src, unsigned short* __restrict__ dst,
             int K, int N) {
    const int i = blockIdx.x * 256 + threadIdx.x;   // over N*K outputs
    if (i >= N * K) return;
    const int n = i / K, k = i % K;
    dst[i] = f2bf(src[(size_t)k * N + n]);
}

// ---------------------------------------------------------------------------
// bf16 MFMA GEMM: C[M,N] = A[M,K] @ Bt[N,K]^T + bias[N]
// 128x128 tile, 256 thr (4 waves, 2x2 of 64x64), BK=32, 16x16x32 MFMA,
// global_load_lds width-16 staging (m97 structure).
// Requires M%128==0, N%128==0, K%32==0.
// ---------------------------------------------------------------------------
template <bool BF16OUT>
__global__ __launch_bounds__(256)
void k_gemm_bf16(const unsigned short* __restrict__ A,
                 const unsigned short* __restrict__ Bt,
                 const float* __restrict__ bias, void* __restrict__ Cout,
                 int M, int N, int K) {
    __shared__ __align__(16) unsigned short As[128 * 32];
    __shared__ __align__(16) unsigned short Bs[128 * 32];

    const int tid  = threadIdx.x;
    const int lane = tid & 63;
    const int w    = tid >> 6;
    const int wm   = w >> 1, wn = w & 1;
    const int m0   = blockIdx.x * 128, n0 = blockIdx.y * 128;

    // staging: thread tid loads row tid/4, 16B chunk tid%4 (and +64 rows)
    const unsigned short* ag0 = A  + (size_t)(m0 + (tid >> 2)) * K + (tid & 3) * 8;
    const unsigned short* ag1 = ag0 + (size_t)64 * K;
    const unsigned short* bg0 = Bt + (size_t)(n0 + (tid >> 2)) * K + (tid & 3) * 8;
    const unsigned short* bg1 = bg0 + (size_t)64 * K;
    unsigned short* al0 = As + tid * 8;
    unsigned short* al1 = As + 2048 + tid * 8;
    unsigned short* bl0 = Bs + tid * 8;
    unsigned short* bl1 = Bs + 2048 + tid * 8;

    // fragment LDS offsets (shorts): row-major [128][32]
    int aoff[4], boff[4];
    #pragma unroll
    for (int t = 0; t < 4; ++t) {
        aoff[t] = (wm * 64 + t * 16 + (lane & 15)) * 32 + (lane >> 4) * 8;
        boff[t] = (wn * 64 + t * 16 + (lane & 15)) * 32 + (lane >> 4) * 8;
    }

    f32x4 acc[4][4];
    #pragma unroll
    for (int i = 0; i < 4; ++i)
        #pragma unroll
        for (int j = 0; j < 4; ++j) acc[i][j] = (f32x4){0.f, 0.f, 0.f, 0.f};

    for (int k0 = 0; k0 < K; k0 += 32) {
        async16(ag0, al0); async16(ag1, al1);
        async16(bg0, bl0); async16(bg1, bl1);
        ag0 += 32; ag1 += 32; bg0 += 32; bg1 += 32;
        __syncthreads();                       // drains vmcnt -> LDS visible

        bf16x8 af[4], bfr[4];
        #pragma unroll
        for (int t = 0; t < 4; ++t) {
            af[t]  = *(const bf16x8*)&As[aoff[t]];
            bfr[t] = *(const bf16x8*)&Bs[boff[t]];
        }
        #pragma unroll
        for (int i = 0; i < 4; ++i)
            #pragma unroll
            for (int j = 0; j < 4; ++j)
                acc[i][j] = __builtin_amdgcn_mfma_f32_16x16x32_bf16(
                    af[i], bfr[j], acc[i][j], 0, 0, 0);
        __syncthreads();                       // protect LDS before next stage
    }

    // epilogue: C/D layout col=lane&15, row=(lane>>4)*4+reg
    const int colb = n0 + wn * 64 + (lane & 15);
    const int rowb = m0 + wm * 64 + (lane >> 4) * 4;
    #pragma unroll
    for (int tn = 0; tn < 4; ++tn) {
        const int col = colb + tn * 16;
        const float bb = bias[col];
        #pragma unroll
        for (int tm = 0; tm < 4; ++tm) {
            #pragma unroll
            for (int r = 0; r < 4; ++r) {
                const int row = rowb + tm * 16 + r;
                const float val = acc[tm][tn][r] + bb;
                if (BF16OUT)
                    ((unsigned short*)Cout)[(size_t)row * N + col] = f2bf(val);
                else
                    ((float*)Cout)[(size_t)row * N + col] = val;
            }
        }
    }
}

// ---------------------------------------------------------------------------
// Kernel C: bilinear sample (bf16 img) + weighted sum over points -> bf16
// One block per (b,q). 256 thr = 4 waves; wave w owns heads {2w, 2w+1};
// lane owns 4 channels (ushort4 loads, 512 B per wave per corner).
// Phase 1: threads 0..31 compute per-(h,p) clamped corner indices and
// attn*validity-premultiplied weights -> LDS (no per-lane recompute,
// unconditional loads).
// ---------------------------------------------------------------------------
__global__ __launch_bounds__(256)
void k_sample(const unsigned short* __restrict__ img,   // [B,H,W,D] bf16
              const float* __restrict__ locs,           // [B,Q,NH,NP,2]
              const float* __restrict__ attnw,          // [B,Q,NH,NP]
              unsigned short* __restrict__ weighted) {  // [B,Q,NH*D] bf16
    const int bq   = blockIdx.x;          // b*Q + q
    const int b    = bq >> 10;            // Q = 1024
    const int tid  = threadIdx.x;
    const int lane = tid & 63;
    const int w    = tid >> 6;

    __shared__ int   s_off[NH * NP][4];   // corner element index (y*W+x), clamped
    __shared__ float s_wgt[NH * NP][4];   // attn * bilinear * valid

    if (tid < NH * NP) {
        const float gx = locs[(size_t)bq * 64 + tid * 2 + 0];
        const float gy = locs[(size_t)bq * 64 + tid * 2 + 1];
        const float a  = attnw[(size_t)bq * 32 + tid];
        const float x  = ((gx + 1.0f) * (float)W - 1.0f) * 0.5f;
        const float y  = ((gy + 1.0f) * (float)H - 1.0f) * 0.5f;
        const float x0f = floorf(x), y0f = floorf(y);
        const float wx1 = x - x0f,  wy1 = y - y0f;
        const float wx0 = 1.0f - wx1, wy0 = 1.0f - wy1;
        const int x0 = (int)x0f, y0 = (int)y0f;
        const int x1 = x0 + 1,  y1 = y0 + 1;
        const float vx0 = (x0 >= 0 && x0 < W) ? 1.0f : 0.0f;
        const float vx1 = (x1 >= 0 && x1 < W) ? 1.0f : 0.0f;
        const float vy0 = (y0 >= 0 && y0 < H) ? 1.0f : 0.0f;
        const float vy1 = (y1 >= 0 && y1 < H) ? 1.0f : 0.0f;
        const int xc0 = min(max(x0, 0), W - 1);
        const int xc1 = min(max(x1, 0), W - 1);
        const int yc0 = min(max(y0, 0), H - 1);
        const int yc1 = min(max(y1, 0), H - 1);
        s_off[tid][0] = yc0 * W + xc0;
        s_off[tid][1] = yc0 * W + xc1;
        s_off[tid][2] = yc1 * W + xc0;
        s_off[tid][3] = yc1 * W + xc1;
        s_wgt[tid][0] = a * wx0 * wy0 * vx0 * vy0;
        s_wgt[tid][1] = a * wx1 * wy0 * vx1 * vy0;
        s_wgt[tid][2] = a * wx0 * wy1 * vx0 * vy1;
        s_wgt[tid][3] = a * wx1 * wy1 * vx1 * vy1;
    }
    __syncthreads();

    const unsigned short* ib = img + (size_t)b * HW * D + lane * 4;

    float acc[2][4] = {};
    #pragma unroll
    for (int i = 0; i < 8; ++i) {              // 2 heads x 4 points
        const int t  = w * 8 + i;              // (h,p) pair index
        const int hh = i >> 2;                 // head within wave
        #pragma unroll
        for (int c = 0; c < 4; ++c) {
            const float wgt = s_wgt[t][c];
            const ushort4v v = *(const ushort4v*)(ib + (size_t)s_off[t][c] * D);
            acc[hh][0] += wgt * bf2f(v.x);
            acc[hh][1] += wgt * bf2f(v.y);
            acc[hh][2] += wgt * bf2f(v.z);
            acc[hh][3] += wgt * bf2f(v.w);
        }
    }

    #pragma unroll
    for (int hh = 0; hh < 2; ++hh) {
        const int h = w * 2 + hh;
        ushort4v o;
        o.x = f2bf(acc[hh][0]); o.y = f2bf(acc[hh][1]);
        o.z = f2bf(acc[hh][2]); o.w = f2bf(acc[hh][3]);
        *(ushort4v*)&weighted[(size_t)bq * (NH * D) + h * D + lane * 4] = o;
    }
}

// ---------------------------------------------------------------------------
extern "C" void kernel_launch(void* const* d_in, const int* in_sizes, int n_in,
                              void* d_out, int out_size, void* d_ws, size_t ws_size,
                              hipStream_t stream) {
    const float* query  = (const float*)d_in[0];
    const float* refpts = (const float*)d_in[1];
    const float* value  = (const float*)d_in[2];
    const float* W_off  = (const float*)d_in[3];
    const float* b_off  = (const float*)d_in[4];
    const float* W_attn = (const float*)d_in[5];
    const float* b_attn = (const float*)d_in[6];
    const float* W_v    = (const float*)d_in[7];
    const float* b_v    = (const float*)d_in[8];
    const float* W_out  = (const float*)d_in[9];
    const float* b_out  = (const float*)d_in[10];
    float* out = (float*)d_out;

    // workspace layout (float slots; all 16B aligned)
    float* ws = (float*)d_ws;
    unsigned short* img_bf  = (unsigned short*)ws;                   // B*HW*D bf16 = 32MB
    unsigned short* val_bf  = (unsigned short*)(ws + 8388608);       // B*HW*D bf16 = 32MB
    float*          locs    = ws + 2 * 8388608;                      // 1MB
    float*          attnw   = locs + 262144;                         // 0.5MB
    unsigned short* Wv_t    = (unsigned short*)(attnw + 131072);     // 128KB
    unsigned short* Wout_t  = (unsigned short*)(attnw + 131072 + 32768); // 1MB
    unsigned short* wtd_bf  = val_bf;  // weighted aliases val_bf (dead after GEMM B)

    // A: offsets + attention weights
    k_offsets<<<B * Q, 128, 0, stream>>>(query, refpts, W_off, b_off,
                                         W_attn, b_attn, locs, attnw);

    // converts
    k_conv<<<(B * HW * D) / 1024, 256, 0, stream>>>(value, val_bf, B * HW * D);
    k_convt<<<(D * D) / 256, 256, 0, stream>>>(W_v, Wv_t, D, D);
    k_convt<<<(NH * D * D) / 256, 256, 0, stream>>>(W_out, Wout_t, NH * D, D);

    // B: img = value @ W_v + b_v   (M=65536, N=256, K=256) -> bf16
    {
        dim3 grid((B * HW) / 128, D / 128);
        k_gemm_bf16<true><<<grid, 256, 0, stream>>>(val_bf, Wv_t, b_v, img_bf,
                                                    B * HW, D, D);
    }

    // C: bilinear sampling + weighted reduce -> bf16 [B*Q, NH*D]
    k_sample<<<B * Q, 256, 0, stream>>>(img_bf, locs, attnw, wtd_bf);

    // D: out = weighted @ W_out + b_out  (M=4096, N=256, K=2048) -> fp32
    {
        dim3 grid((B * Q) / 128, D / 128);
        k_gemm_bf16<false><<<grid, 256, 0, stream>>>(wtd_bf, Wout_t, b_out, out,
                                                     B * Q, D, NH * D);
    }
}

// Round 4
// 210.162 us; speedup vs baseline: 2.2398x; 1.1432x over previous
//
#include <hip/hip_runtime.h>
#include <hip/hip_bf16.h>
#include <math.h>

// Problem constants (fixed by setup_inputs)
constexpr int B  = 4;
constexpr int Q  = 1024;
constexpr int D  = 256;
constexpr int NH = 8;
constexpr int NP = 4;
constexpr int H  = 128;
constexpr int W  = 128;
constexpr int HW = H * W;
constexpr int KAUG = 2112;          // 8*256 channels + 8 S + 56 zeros (K % 64 == 0)

typedef short   bf16x8  __attribute__((ext_vector_type(8)));
typedef float   f32x4   __attribute__((ext_vector_type(4)));
typedef short   short4v __attribute__((ext_vector_type(4)));
typedef unsigned short ushort4v __attribute__((ext_vector_type(4)));

__device__ inline unsigned short f2bf(float f) {
    union { float f; unsigned u; } v; v.f = f;
    unsigned r = v.u + 0x7fff + ((v.u >> 16) & 1);   // RNE
    return (unsigned short)(r >> 16);
}
__device__ inline float bf2f(unsigned short s) {
    union { unsigned u; float f; } v; v.u = ((unsigned)s) << 16;
    return v.f;
}

// async global->LDS, 16B per lane. LDS dest = wave-uniform base + lane*16.
__device__ inline void async16(const void* g, void* l) {
    __builtin_amdgcn_global_load_lds(
        (const __attribute__((address_space(1))) unsigned*)g,
        (__attribute__((address_space(3))) unsigned*)l, 16, 0, 0);
}

// ---------------------------------------------------------------------------
// Kernel A: offsets + attention logits + softmax -> locs, attn weights
// ---------------------------------------------------------------------------
__global__ __launch_bounds__(128)
void k_offsets(const float* __restrict__ query,
               const float* __restrict__ refpts,
               const float* __restrict__ W_off,  const float* __restrict__ b_off,
               const float* __restrict__ W_attn, const float* __restrict__ b_attn,
               float* __restrict__ locs, float* __restrict__ attnw) {
    const int bq = blockIdx.x;
    const int t  = threadIdx.x;
    __shared__ float qrow[D];
    __shared__ float logits[NH * NP];

    const float* qp = query + (size_t)bq * D;
    for (int i = t; i < D; i += 128) qrow[i] = qp[i];
    __syncthreads();

    if (t < 64) {
        float acc = b_off[t];
        #pragma unroll 4
        for (int k = 0; k < D; ++k) acc += qrow[k] * W_off[k * 64 + t];
        const int c = t & 1;
        const float ref = refpts[(size_t)bq * 2 + c];
        float loc = ref + acc * 0.1f;
        loc = fminf(fmaxf(loc, 0.0f), 1.0f) * 2.0f - 1.0f;
        locs[(size_t)bq * 64 + t] = loc;
    } else if (t < 96) {
        const int j = t - 64;
        float acc = b_attn[j];
        #pragma unroll 4
        for (int k = 0; k < D; ++k) acc += qrow[k] * W_attn[k * 32 + j];
        logits[j] = acc;
    }
    __syncthreads();

    if (t < NH) {
        float m = -1e30f;
        #pragma unroll
        for (int p = 0; p < NP; ++p) m = fmaxf(m, logits[t * NP + p]);
        float e[NP]; float s = 0.0f;
        #pragma unroll
        for (int p = 0; p < NP; ++p) { e[p] = __expf(logits[t * NP + p] - m); s += e[p]; }
        const float inv = 1.0f / s;
        #pragma unroll
        for (int p = 0; p < NP; ++p)
            attnw[(size_t)bq * (NH * NP) + t * NP + p] = e[p] * inv;
    }
}

// ---------------------------------------------------------------------------
// fp32 -> bf16 elementwise convert (vectorized, n % 1024 == 0)
// ---------------------------------------------------------------------------
__global__ __launch_bounds__(256)
void k_conv(const float* __restrict__ src, unsigned short* __restrict__ dst, int n) {
    const int i = (blockIdx.x * 256 + threadIdx.x) * 4;
    if (i >= n) return;
    const float4 v = *(const float4*)&src[i];
    short4v o;
    o.x = (short)f2bf(v.x); o.y = (short)f2bf(v.y);
    o.z = (short)f2bf(v.z); o.w = (short)f2bf(v.w);
    *(short4v*)&dst[i] = o;
}

// ---------------------------------------------------------------------------
// fp32 [K,N] -> bf16 transposed [N,K]
// ---------------------------------------------------------------------------
__global__ __launch_bounds__(256)
void k_convt(const float* __restrict__ src, unsigned short* __restrict__ dst,
             int K, int N) {
    const int i = blockIdx.x * 256 + threadIdx.x;
    if (i >= N * K) return;
    const int n = i / K, k = i % K;
    dst[i] = f2bf(src[(size_t)k * N + n]);
}

// ---------------------------------------------------------------------------
// Border-correction columns of WcT: WcT[n, 2048+h] = sum_j b_v[j]*W_out[h*256+j, n]
// (cols 2056..2111 zeroed). Exact handling of b_v through the commuted pipeline.
// ---------------------------------------------------------------------------
__global__ __launch_bounds__(256)
void k_bvout(const float* __restrict__ b_v, const float* __restrict__ W_out,
             unsigned short* __restrict__ WcT) {
    const int t = blockIdx.x * 256 + threadIdx.x;   // 16384 threads: n = t>>6, c = t&63
    if (t >= 256 * 64) return;
    const int n = t >> 6, c = t & 63;
    float v = 0.0f;
    if (c < 8) {
        #pragma unroll 8
        for (int j = 0; j < D; ++j)
            v += b_v[j] * W_out[((size_t)c * D + j) * D + n];
    }
    WcT[(size_t)n * KAUG + 2048 + c] = f2bf(v);
}

// ---------------------------------------------------------------------------
// bf16 MFMA GEMM, 64x64 tile, BK=64, double-buffered async16 staging,
// XOR-swizzled LDS (chunk c stored at c^(row&7); staging stays lane-contiguous).
// 256 thr = 4 waves in 2x2, each wave 32x32 (2x2 of 16x16x32 frags).
// C[M,N] = A[M,K](lda) @ Bt[N,K](ldb)^T
// OUTMODE 0: fp32 C row-major (ldc) + bias[N]
// OUTMODE 1: bf16 transposed store Wt[col*ldc + z*256 + row]; Bt += z*256 (batched)
// ---------------------------------------------------------------------------
template <int OUTMODE>
__global__ __launch_bounds__(256)
void k_gemm64(const unsigned short* __restrict__ A, int lda,
              const unsigned short* __restrict__ Bt, int ldb,
              const float* __restrict__ bias,
              void* __restrict__ Cout, int ldc, int K) {
    __shared__ __align__(16) unsigned short lds[4][4096];  // As0,Bs0,As1,Bs1

    const int tid  = threadIdx.x;
    const int lane = tid & 63;
    const int w    = tid >> 6;
    const int wm   = w >> 1, wn = w & 1;
    const int m0 = blockIdx.x * 64, n0 = blockIdx.y * 64;
    if (OUTMODE == 1) Bt += (size_t)blockIdx.z * 256;

    // staging: lane l of wave w covers rows w*8+(l>>3) and +32; logical chunk (l&7)^(l>>3)
    const int srow = w * 8 + (lane >> 3);
    const int schk = (lane & 7) ^ (lane >> 3);
    const unsigned short* ag0 = A  + (size_t)(m0 + srow)      * lda + schk * 8;
    const unsigned short* ag1 = A  + (size_t)(m0 + srow + 32) * lda + schk * 8;
    const unsigned short* bg0 = Bt + (size_t)(n0 + srow)      * ldb + schk * 8;
    const unsigned short* bg1 = Bt + (size_t)(n0 + srow + 32) * ldb + schk * 8;
    const int l0 = w * 512 + lane * 8;
    const int l1 = l0 + 2048;

    // fragment offsets (shorts) in [64][64] swizzled buffer
    int aoff[2][2], boff[2][2];
    #pragma unroll
    for (int i = 0; i < 2; ++i)
        #pragma unroll
        for (int kk = 0; kk < 2; ++kk) {
            const int ar = wm * 32 + i * 16 + (lane & 15);
            aoff[i][kk] = ar * 64 + ((((lane >> 4) + kk * 4) ^ (ar & 7)) * 8);
            const int br = wn * 32 + i * 16 + (lane & 15);
            boff[i][kk] = br * 64 + ((((lane >> 4) + kk * 4) ^ (br & 7)) * 8);
        }

    f32x4 acc[2][2];
    #pragma unroll
    for (int i = 0; i < 2; ++i)
        #pragma unroll
        for (int j = 0; j < 2; ++j) acc[i][j] = (f32x4){0.f, 0.f, 0.f, 0.f};

    // preload stage 0
    async16(ag0, &lds[0][l0]); async16(ag1, &lds[0][l1]);
    async16(bg0, &lds[1][l0]); async16(bg1, &lds[1][l1]);

    const int niter = K >> 6;
    for (int it = 0; it < niter; ++it) {
        __syncthreads();                       // drains vmcnt -> stage `it` ready
        const int cur = (it & 1) * 2;
        if (it + 1 < niter) {                  // prefetch next stage during compute
            const int nxt = 2 - cur;
            const int ko  = (it + 1) * 64;
            async16(ag0 + ko, &lds[nxt][l0]);
            async16(ag1 + ko, &lds[nxt][l1]);
            async16(bg0 + ko, &lds[nxt + 1][l0]);
            async16(bg1 + ko, &lds[nxt + 1][l1]);
        }
        bf16x8 af[2][2], bfv[2][2];
        #pragma unroll
        for (int i = 0; i < 2; ++i)
            #pragma unroll
            for (int kk = 0; kk < 2; ++kk) {
                af[i][kk]  = *(const bf16x8*)&lds[cur][aoff[i][kk]];
                bfv[i][kk] = *(const bf16x8*)&lds[cur + 1][boff[i][kk]];
            }
        #pragma unroll
        for (int i = 0; i < 2; ++i)
            #pragma unroll
            for (int j = 0; j < 2; ++j)
                #pragma unroll
                for (int kk = 0; kk < 2; ++kk)
                    acc[i][j] = __builtin_amdgcn_mfma_f32_16x16x32_bf16(
                        af[i][kk], bfv[j][kk], acc[i][j], 0, 0, 0);
    }

    // epilogue: C/D layout col=lane&15, row=(lane>>4)*4+reg
    const int colb = n0 + wn * 32 + (lane & 15);
    const int rowb = m0 + wm * 32 + (lane >> 4) * 4;
    if (OUTMODE == 0) {
        float* C = (float*)Cout;
        #pragma unroll
        for (int j = 0; j < 2; ++j) {
            const int col = colb + j * 16;
            const float bb = bias[col];
            #pragma unroll
            for (int i = 0; i < 2; ++i)
                #pragma unroll
                for (int r = 0; r < 4; ++r)
                    C[(size_t)(rowb + i * 16 + r) * ldc + col] = acc[i][j][r] + bb;
        }
    } else {
        unsigned short* Wt = (unsigned short*)Cout;
        const int ocol = blockIdx.z * 256;
        #pragma unroll
        for (int j = 0; j < 2; ++j) {
            const int col = colb + j * 16;
            #pragma unroll
            for (int i = 0; i < 2; ++i)
                #pragma unroll
                for (int r = 0; r < 4; ++r)
                    Wt[(size_t)col * ldc + ocol + rowb + i * 16 + r] =
                        f2bf(acc[i][j][r]);
        }
    }
}

// ---------------------------------------------------------------------------
// Kernel C: bilinear sample raw value (bf16) + weighted sum over points -> sv
// One block per (b,q). 256 thr = 4 waves; wave w owns heads {2w, 2w+1};
// lane owns 4 channels. Also writes S_h (attn-weighted corner-validity sums)
// into augmented cols 2048+h, zeros in 2056..2111.
// ---------------------------------------------------------------------------
__global__ __launch_bounds__(256)
void k_sample(const unsigned short* __restrict__ val,   // [B,H,W,D] bf16 (raw value)
              const float* __restrict__ locs,           // [B,Q,NH,NP,2]
              const float* __restrict__ attnw,          // [B,Q,NH,NP]
              unsigned short* __restrict__ sv) {        // [B*Q, KAUG] bf16
    const int bq   = blockIdx.x;          // b*Q + q
    const int b    = bq >> 10;            // Q = 1024
    const int tid  = threadIdx.x;
    const int lane = tid & 63;
    const int w    = tid >> 6;

    __shared__ int   s_off[NH * NP][4];   // corner element index (y*W+x), clamped
    __shared__ float s_wgt[NH * NP][4];   // attn * bilinear * valid

    if (tid < NH * NP) {
        const float gx = locs[(size_t)bq * 64 + tid * 2 + 0];
        const float gy = locs[(size_t)bq * 64 + tid * 2 + 1];
        const float a  = attnw[(size_t)bq * 32 + tid];
        const float x  = ((gx + 1.0f) * (float)W - 1.0f) * 0.5f;
        const float y  = ((gy + 1.0f) * (float)H - 1.0f) * 0.5f;
        const float x0f = floorf(x), y0f = floorf(y);
        const float wx1 = x - x0f,  wy1 = y - y0f;
        const float wx0 = 1.0f - wx1, wy0 = 1.0f - wy1;
        const int x0 = (int)x0f, y0 = (int)y0f;
        const int x1 = x0 + 1,  y1 = y0 + 1;
        const float vx0 = (x0 >= 0 && x0 < W) ? 1.0f : 0.0f;
        const float vx1 = (x1 >= 0 && x1 < W) ? 1.0f : 0.0f;
        const float vy0 = (y0 >= 0 && y0 < H) ? 1.0f : 0.0f;
        const float vy1 = (y1 >= 0 && y1 < H) ? 1.0f : 0.0f;
        const int xc0 = min(max(x0, 0), W - 1);
        const int xc1 = min(max(x1, 0), W - 1);
        const int yc0 = min(max(y0, 0), H - 1);
        const int yc1 = min(max(y1, 0), H - 1);
        s_off[tid][0] = yc0 * W + xc0;
        s_off[tid][1] = yc0 * W + xc1;
        s_off[tid][2] = yc1 * W + xc0;
        s_off[tid][3] = yc1 * W + xc1;
        s_wgt[tid][0] = a * wx0 * wy0 * vx0 * vy0;
        s_wgt[tid][1] = a * wx1 * wy0 * vx1 * vy0;
        s_wgt[tid][2] = a * wx0 * wy1 * vx0 * vy1;
        s_wgt[tid][3] = a * wx1 * wy1 * vx1 * vy1;
    }
    __syncthreads();

    // augmented columns: S_h and zero padding
    if (tid < 8) {
        float S = 0.0f;
        #pragma unroll
        for (int p = 0; p < NP; ++p)
            #pragma unroll
            for (int c = 0; c < 4; ++c) S += s_wgt[tid * 4 + p][c];
        sv[(size_t)bq * KAUG + 2048 + tid] = f2bf(S);
    } else if (tid < 64) {
        sv[(size_t)bq * KAUG + 2048 + tid] = 0;
    }

    const unsigned short* ib = val + (size_t)b * HW * D + lane * 4;

    float acc[2][4] = {};
    #pragma unroll
    for (int i = 0; i < 8; ++i) {              // 2 heads x 4 points
        const int t  = w * 8 + i;
        const int hh = i >> 2;
        #pragma unroll
        for (int c = 0; c < 4; ++c) {
            const float wgt = s_wgt[t][c];
            const ushort4v v = *(const ushort4v*)(ib + (size_t)s_off[t][c] * D);
            acc[hh][0] += wgt * bf2f(v.x);
            acc[hh][1] += wgt * bf2f(v.y);
            acc[hh][2] += wgt * bf2f(v.z);
            acc[hh][3] += wgt * bf2f(v.w);
        }
    }

    #pragma unroll
    for (int hh = 0; hh < 2; ++hh) {
        const int h = w * 2 + hh;
        ushort4v o;
        o.x = f2bf(acc[hh][0]); o.y = f2bf(acc[hh][1]);
        o.z = f2bf(acc[hh][2]); o.w = f2bf(acc[hh][3]);
        *(ushort4v*)&sv[(size_t)bq * KAUG + h * D + lane * 4] = o;
    }
}

// ---------------------------------------------------------------------------
extern "C" void kernel_launch(void* const* d_in, const int* in_sizes, int n_in,
                              void* d_out, int out_size, void* d_ws, size_t ws_size,
                              hipStream_t stream) {
    const float* query  = (const float*)d_in[0];
    const float* refpts = (const float*)d_in[1];
    const float* value  = (const float*)d_in[2];
    const float* W_off  = (const float*)d_in[3];
    const float* b_off  = (const float*)d_in[4];
    const float* W_attn = (const float*)d_in[5];
    const float* b_attn = (const float*)d_in[6];
    const float* W_v    = (const float*)d_in[7];
    const float* b_v    = (const float*)d_in[8];
    const float* W_out  = (const float*)d_in[9];
    const float* b_out  = (const float*)d_in[10];
    float* out = (float*)d_out;

    // workspace layout (byte offsets, all 256B aligned)
    char* wsb = (char*)d_ws;
    unsigned short* val_bf = (unsigned short*)(wsb);             // B*HW*D bf16   = 33,554,432 B
    unsigned short* sv     = (unsigned short*)(wsb + 33554432);  // 4096*2112 bf16= 17,301,504 B
    unsigned short* WcT    = (unsigned short*)(wsb + 50855936);  // 256*2112 bf16 =  1,081,344 B
    unsigned short* Wout_t = (unsigned short*)(wsb + 51937280);  // 256*2048 bf16 =  1,048,576 B
    unsigned short* Wv_bf  = (unsigned short*)(wsb + 52985856);  // 256*256 bf16  =    131,072 B
    float*          locs   = (float*)(wsb + 53116928);           // 262144 f32    =  1,048,576 B
    float*          attnw  = (float*)(wsb + 54165504);           // 131072 f32    =    524,288 B

    // A: offsets + attention weights
    k_offsets<<<B * Q, 128, 0, stream>>>(query, refpts, W_off, b_off,
                                         W_attn, b_attn, locs, attnw);

    // converts
    k_conv<<<(B * HW * D) / 1024, 256, 0, stream>>>(value, val_bf, B * HW * D);
    k_conv<<<(D * D) / 1024, 256, 0, stream>>>(W_v, Wv_bf, D * D);
    k_convt<<<(NH * D * D) / 256, 256, 0, stream>>>(W_out, Wout_t, NH * D, D);

    // Wc_h = W_v @ W_out_h  -> WcT[n, h*256+i] (batched over h = blockIdx.z)
    {
        dim3 grid(D / 64, D / 64, NH);
        k_gemm64<1><<<grid, 256, 0, stream>>>(Wv_bf, D, Wout_t, NH * D,
                                              nullptr, WcT, KAUG, D);
    }
    // WcT border-correction cols (b_v @ W_out_h), cols 2048..2111
    k_bvout<<<64, 256, 0, stream>>>(b_v, W_out, WcT);

    // sample raw value + weighted reduce -> sv [4096, KAUG]
    k_sample<<<B * Q, 256, 0, stream>>>(val_bf, locs, attnw, sv);

    // out = sv @ WcT^T + b_out  (M=4096, N=256, K=2112)
    {
        dim3 grid((B * Q) / 64, D / 64, 1);
        k_gemm64<0><<<grid, 256, 0, stream>>>(sv, KAUG, WcT, KAUG,
                                              b_out, out, D, KAUG);
    }
}